// Round 4
// baseline (4622.083 us; speedup 1.0000x reference)
//
#include <hip/hip_runtime.h>
#include <math.h>

__device__ __forceinline__ float fast_rcp(float x) { return __builtin_amdgcn_rcpf(x); }

// Compiler-level memory fence: blocks hoisting/CSE of LDS & global loads
// across this point. Register-promoted locals (SSA values) are unaffected.
#define MEMFENCE() asm volatile("" ::: "memory")

// Softplus + sigmoid with HW instructions only (v_exp_f32 / v_log_f32 / v_rcp_f32).
__device__ __forceinline__ void sp_sig(float z, float& h, float& s) {
    float az = fabsf(z);
    float e  = __expf(-az);
    float r  = fast_rcp(1.0f + e);
    h = fmaxf(z, 0.0f) + __logf(1.0f + e);
    s = (z >= 0.0f) ? r : (1.0f - r);
}

__global__ __launch_bounds__(256) void energy_kernel(
    const float* __restrict__ Fg,
    const float* __restrict__ W0, const float* __restrict__ b0,
    const float* __restrict__ W1, const float* __restrict__ b1,
    const float* __restrict__ W2, const float* __restrict__ b2,
    float* __restrict__ P, float* __restrict__ Wv, int n)
{
    // LDS weight layout:
    //   [0..255]    w0t[32][8] : {W0[0..5][k], b0[k], pad}  (32B rows -> b128)
    //   [256..1279] w1 [32][32] rows
    //   [1280..1311] b1, [1312..1343] w2, [1344] b2
    __shared__ float lw[1345];
    const int tid = threadIdx.x;
    if (tid < 32) {
        #pragma unroll
        for (int m = 0; m < 6; ++m) lw[tid * 8 + m] = W0[m * 32 + tid];
        lw[tid * 8 + 6] = b0[tid];
        lw[tid * 8 + 7] = 0.0f;
        lw[1280 + tid] = b1[tid];
        lw[1312 + tid] = W2[tid];
    }
    #pragma unroll
    for (int i = 0; i < 1024; i += 256) lw[256 + i + tid] = W1[i + tid];
    if (tid == 0) lw[1344] = b2[0];
    __syncthreads();

    int idx = blockIdx.x * blockDim.x + tid;
    if (idx >= n) return;

    const float* f = Fg + (size_t)idx * 9;

    // ---- invariants (F regs die after this block) ----
    float iv0, iv1, iv2, iv4, iv5;
    {
        float f00=f[0], f01=f[1], f02=f[2];
        float f10=f[3], f11=f[4], f12=f[5];
        float f20=f[6], f21=f[7], f22=f[8];

        float c00 = f00*f00 + f10*f10 + f20*f20;
        float c01 = f00*f01 + f10*f11 + f20*f21;
        float c02 = f00*f02 + f10*f12 + f20*f22;
        float c11 = f01*f01 + f11*f11 + f21*f21;
        float c12 = f01*f02 + f11*f12 + f21*f22;
        float c22 = f02*f02 + f12*f12 + f22*f22;

        float A00 = c11*c22 - c12*c12;
        float A01 = c02*c12 - c01*c22;
        float A02 = c01*c12 - c02*c11;
        float A11 = c00*c22 - c02*c02;
        float A12 = c01*c02 - c00*c12;
        float A22 = c00*c11 - c01*c01;

        iv0 = c00 + c11 + c22;
        iv1 = A00 + A11 + A22;
        iv2 = f00*(f11*f22 - f12*f21) - f01*(f10*f22 - f12*f20) + f02*(f10*f21 - f11*f20);
        iv4 = c00*c00 + c11*c11 + c22*c22;
        iv5 = A00*A00 + A11*A11 + A22*A22;
    }
    MEMFENCE();

    // ---- Phase A: fused layer0 + layer1 (h0[k] consumed immediately) ----
    float s0[32];
    float z1[32];
    #pragma unroll
    for (int j = 0; j < 32; ++j) z1[j] = lw[1280 + j];

    #pragma unroll
    for (int k = 0; k < 32; ++k) {
        float4 wa = *(const float4*)(lw + k * 8);      // W0[0..3][k]
        float4 wb = *(const float4*)(lw + k * 8 + 4);  // W0[4],W0[5],b0,pad
        float z = wb.z;
        z = fmaf(iv0, wa.x, z);
        z = fmaf(iv1, wa.y, z);
        z = fmaf(iv2, wa.z, z);
        z = fmaf(-iv2, wa.w, z);
        z = fmaf(iv4, wb.x, z);
        z = fmaf(iv5, wb.y, z);
        float hk, sk;
        sp_sig(z, hk, sk);
        s0[k] = sk;
        #pragma unroll
        for (int j4 = 0; j4 < 8; ++j4) {
            float4 w = *(const float4*)(lw + 256 + k * 32 + j4 * 4);
            z1[j4*4+0] = fmaf(hk, w.x, z1[j4*4+0]);
            z1[j4*4+1] = fmaf(hk, w.y, z1[j4*4+1]);
            z1[j4*4+2] = fmaf(hk, w.z, z1[j4*4+2]);
            z1[j4*4+3] = fmaf(hk, w.w, z1[j4*4+3]);
        }
        if ((k & 1) == 1) MEMFENCE();   // bound LDS-load hoisting window
    }

    // ---- Phase B: output layer + g1 (z1 -> g1) ----
    float g1[32];
    {
        float o0=0.f, o1=0.f, o2=0.f, o3=0.f;
        #pragma unroll
        for (int j = 0; j < 32; ++j) {
            float h1, s1;
            sp_sig(z1[j], h1, s1);
            float w2 = lw[1312 + j];
            if ((j & 3) == 0)      o0 = fmaf(h1, w2, o0);
            else if ((j & 3) == 1) o1 = fmaf(h1, w2, o1);
            else if ((j & 3) == 2) o2 = fmaf(h1, w2, o2);
            else                   o3 = fmaf(h1, w2, o3);
            g1[j] = w2 * s1;
            if ((j & 7) == 7) MEMFENCE();
        }
        Wv[idx] = (o0 + o1) + (o2 + o3) + lw[1344];
    }
    MEMFENCE();

    // ---- Phase C: backward, d[m] = dOut/d iv[m] ----
    float d0=0.f, d1=0.f, d2r=0.f, d3r=0.f, d4=0.f, d5=0.f;
    #pragma unroll
    for (int k = 0; k < 32; ++k) {
        float p0=0.f, p1=0.f, p2=0.f, p3=0.f;
        #pragma unroll
        for (int j4 = 0; j4 < 8; ++j4) {
            float4 w = *(const float4*)(lw + 256 + k * 32 + j4 * 4);
            p0 = fmaf(w.x, g1[j4*4+0], p0);
            p1 = fmaf(w.y, g1[j4*4+1], p1);
            p2 = fmaf(w.z, g1[j4*4+2], p2);
            p3 = fmaf(w.w, g1[j4*4+3], p3);
        }
        float g0k = ((p0 + p1) + (p2 + p3)) * s0[k];
        float4 wa = *(const float4*)(lw + k * 8);
        float4 wb = *(const float4*)(lw + k * 8 + 4);
        d0  = fmaf(wa.x, g0k, d0);
        d1  = fmaf(wa.y, g0k, d1);
        d2r = fmaf(wa.z, g0k, d2r);
        d3r = fmaf(wa.w, g0k, d3r);
        d4  = fmaf(wb.x, g0k, d4);
        d5  = fmaf(wb.y, g0k, d5);
        if ((k & 1) == 1) MEMFENCE();   // bound LDS-load hoisting window
    }
    MEMFENCE();

    // ---- Phase D: epilogue, reload F (L2/L3-warm), P = F*M + (d2-d3)*cof(F) ----
    float f00=f[0], f01=f[1], f02=f[2];
    float f10=f[3], f11=f[4], f12=f[5];
    float f20=f[6], f21=f[7], f22=f[8];

    float c00 = f00*f00 + f10*f10 + f20*f20;
    float c01 = f00*f01 + f10*f11 + f20*f21;
    float c02 = f00*f02 + f10*f12 + f20*f22;
    float c11 = f01*f01 + f11*f11 + f21*f21;
    float c12 = f01*f02 + f11*f12 + f21*f22;
    float c22 = f02*f02 + f12*f12 + f22*f22;

    float A00 = c11*c22 - c12*c12;
    float A01 = c02*c12 - c01*c22;
    float A02 = c01*c12 - c02*c11;
    float A11 = c00*c22 - c02*c02;
    float A12 = c01*c02 - c00*c12;
    float A22 = c00*c11 - c01*c01;

    float cf00 = f11*f22 - f12*f21;
    float cf01 = f12*f20 - f10*f22;
    float cf02 = f10*f21 - f11*f20;
    float cf10 = f02*f21 - f01*f22;
    float cf11 = f00*f22 - f02*f20;
    float cf12 = f01*f20 - f00*f21;
    float cf20 = f01*f12 - f02*f11;
    float cf21 = f02*f10 - f00*f12;
    float cf22 = f00*f11 - f01*f10;
    float J  = f00*cf00 + f01*cf01 + f02*cf02;
    float I1 = c00 + c11 + c22;
    float I11v = A00*A00 + A11*A11 + A22*A22;

    float inv2 = 2.0f * fast_rcp(J * J);

    float T00 = A00*A00*A00 + A11*A01*A01 + A22*A02*A02;
    float T01 = A00*A00*A01 + A11*A01*A11 + A22*A02*A12;
    float T02 = A00*A00*A02 + A11*A01*A12 + A22*A02*A22;
    float T11 = A00*A01*A01 + A11*A11*A11 + A22*A12*A12;
    float T12 = A00*A01*A02 + A11*A11*A12 + A22*A12*A22;
    float T22 = A00*A02*A02 + A11*A12*A12 + A22*A22*A22;

    float G00 = inv2 * (I11v*A00 - T00);
    float G01 = inv2 * (I11v*A01 - T01);
    float G02 = inv2 * (I11v*A02 - T02);
    float G11e= inv2 * (I11v*A11 - T11);
    float G12 = inv2 * (I11v*A12 - T12);
    float G22 = inv2 * (I11v*A22 - T22);

    float aJ  = d2r - d3r;
    float t1  = 2.0f * d0;
    float t2  = 2.0f * d1;
    float t7  = 4.0f * d4;
    float t11 = 2.0f * d5;

    float m00 = t1 + t2*(I1 - c00) + t7*c00 + t11*G00;
    float m01 =      -t2*c01               + t11*G01;
    float m02 =      -t2*c02               + t11*G02;
    float m11 = t1 + t2*(I1 - c11) + t7*c11 + t11*G11e;
    float m12 =      -t2*c12               + t11*G12;
    float m22 = t1 + t2*(I1 - c22) + t7*c22 + t11*G22;

    float* p = P + (size_t)idx * 9;
    p[0] = f00*m00 + f01*m01 + f02*m02 + aJ*cf00;
    p[1] = f00*m01 + f01*m11 + f02*m12 + aJ*cf01;
    p[2] = f00*m02 + f01*m12 + f02*m22 + aJ*cf02;
    p[3] = f10*m00 + f11*m01 + f12*m02 + aJ*cf10;
    p[4] = f10*m01 + f11*m11 + f12*m12 + aJ*cf11;
    p[5] = f10*m02 + f11*m12 + f12*m22 + aJ*cf12;
    p[6] = f20*m00 + f21*m01 + f22*m02 + aJ*cf20;
    p[7] = f20*m01 + f21*m11 + f22*m12 + aJ*cf21;
    p[8] = f20*m02 + f21*m12 + f22*m22 + aJ*cf22;
}

extern "C" void kernel_launch(void* const* d_in, const int* in_sizes, int n_in,
                              void* d_out, int out_size, void* d_ws, size_t ws_size,
                              hipStream_t stream) {
    const float* F  = (const float*)d_in[0];
    const float* W0 = (const float*)d_in[1];
    const float* b0 = (const float*)d_in[2];
    const float* W1 = (const float*)d_in[3];
    const float* b1 = (const float*)d_in[4];
    const float* W2 = (const float*)d_in[5];
    const float* b2 = (const float*)d_in[6];
    int n = in_sizes[0] / 9;
    float* out = (float*)d_out;
    float* P  = out;                       // [n,3,3] flat
    float* Wv = out + (size_t)n * 9;       // [n,1] flat

    int block = 256;
    int grid = (n + block - 1) / block;
    hipLaunchKernelGGL(energy_kernel, dim3(grid), dim3(block), 0, stream,
                       F, W0, b0, W1, b1, W2, b2, P, Wv, n);
}

// Round 5
// 135.931 us; speedup vs baseline: 34.0032x; 34.0032x over previous
//
#include <hip/hip_runtime.h>
#include <math.h>

typedef __attribute__((ext_vector_type(8)))  short  bf16x8;
typedef __attribute__((ext_vector_type(16))) float  f32x16;

union FragU { unsigned u[4]; bf16x8 s; };

__device__ __forceinline__ float fast_rcp(float x) { return __builtin_amdgcn_rcpf(x); }

// pack two f32 -> two bf16 in one u32 (lo = first elem), RNE (guide recipe, no builtin)
__device__ __forceinline__ unsigned cvtpk(float lo, float hi) {
    unsigned r;
    asm("v_cvt_pk_bf16_f32 %0, %1, %2" : "=v"(r) : "v"(lo), "v"(hi));
    return r;
}
__device__ __forceinline__ unsigned pswapu(unsigned x) { return (unsigned)__shfl_xor((int)x, 32, 64); }
__device__ __forceinline__ float    pswapf(float x)    { return __shfl_xor(x, 32, 64); }
__device__ __forceinline__ float bfl(unsigned p) { return __uint_as_float(p << 16); }
__device__ __forceinline__ float bfh(unsigned p) { return __uint_as_float(p & 0xffff0000u); }

// Softplus + sigmoid with HW instructions (v_exp_f32 / v_log_f32 / v_rcp_f32).
__device__ __forceinline__ void sp_sig(float z, float& h, float& s) {
    float az = fabsf(z);
    float e  = __expf(-az);
    float r  = fast_rcp(1.0f + e);
    h = fmaxf(z, 0.0f) + __logf(1.0f + e);
    s = (z >= 0.0f) ? r : (1.0f - r);
}

// Build one K=16 B-fragment from 4 packed pairs (C-register pairs covering the
// 16 rows this lane holds). C-layout: reg r of lane-half h -> row (r&3)+8*(r>>2)+4h.
// B-layout: lane-half h' holds k = h'*8 + e. Lane-half exchange via shfl_xor(32).
__device__ __forceinline__ FragU bfrag(bool low, unsigned a0, unsigned a1, unsigned a2, unsigned a3) {
    unsigned s0 = pswapu(a0), s1 = pswapu(a1), s2 = pswapu(a2), s3 = pswapu(a3);
    FragU f;
    f.u[0] = low ? a0 : s2;   // k pair (0,1)  : rows (0,1)  / (8,9)
    f.u[1] = low ? a1 : s3;   // k pair (2,3)  : rows (2,3)  / (10,11)
    f.u[2] = low ? s0 : a2;   // k pair (4,5)  : rows (4,5)  / (12,13)
    f.u[3] = low ? s1 : a3;   // k pair (6,7)  : rows (6,7)  / (14,15)
    return f;
}

__global__ __launch_bounds__(256) void energy_kernel(
    const float* __restrict__ Fg,
    const float* __restrict__ W0, const float* __restrict__ b0,
    const float* __restrict__ W1, const float* __restrict__ b1,
    const float* __restrict__ W2, const float* __restrict__ b2,
    float* __restrict__ P, float* __restrict__ Wv, int n)
{
    const int  tid  = threadIdx.x;
    const int  lane = tid & 63;
    const int  wid  = tid >> 6;
    const int  col  = lane & 31;     // A-row index / B-col (sample-within-tile)
    const int  half = lane >> 5;     // lane half
    const bool low  = (half == 0);
    const long wave_base = ((long)blockIdx.x * 4 + wid) * 64;
    const long idx  = wave_base + lane;      // this lane's sample
    const long cidx = (idx < n) ? idx : 0;   // clamped (n is a multiple of 64 anyway)

    // ---------------- weight A-fragments (bf16), per-lane loads ----------------
    // A-layout (32x32x16): lane holds row = lane&31, k = (lane>>5)*8 + e, e=0..7.
    FragU w0t, w1t[2], w1f[2], w0b[2];
    #pragma unroll
    for (int p = 0; p < 4; ++p) {                    // A = [W0^T | b0 | 0] (K=16)
        const int k0 = half*8 + 2*p, k1 = k0 + 1;
        float lo = (k0 < 6) ? W0[k0*32 + col] : ((k0 == 6) ? b0[col] : 0.f);
        float hi = (k1 < 6) ? W0[k1*32 + col] : ((k1 == 6) ? b0[col] : 0.f);
        w0t.u[p] = cvtpk(lo, hi);
    }
    #pragma unroll
    for (int hf = 0; hf < 2; ++hf) {
        #pragma unroll
        for (int p = 0; p < 4; ++p) {
            const int k0 = hf*16 + half*8 + 2*p, k1 = k0 + 1;
            w1t[hf].u[p] = cvtpk(W1[k0*32 + col], W1[k1*32 + col]);   // A = W1^T
            w1f[hf].u[p] = cvtpk(W1[col*32 + k0], W1[col*32 + k1]);   // A = W1
            float lo = (col < 6) ? W0[col*32 + k0] : 0.f;             // A = W0 (rows 0..5)
            float hi = (col < 6) ? W0[col*32 + k1] : 0.f;
            w0b[hf].u[p] = cvtpk(lo, hi);
        }
    }
    // b1 / W2 packed by C-layout register pairs
    unsigned b1p[8], w2p[8];
    #pragma unroll
    for (int p = 0; p < 8; ++p) {
        const int r0 = 2*p, r1 = r0 + 1;
        const int R0 = (r0 & 3) + 8*(r0 >> 2) + 4*half;
        const int R1 = (r1 & 3) + 8*(r1 >> 2) + 4*half;
        b1p[p] = cvtpk(b1[R0], b1[R1]);
        w2p[p] = cvtpk(W2[R0], W2[R1]);
    }
    const float b2v = b2[0];

    // ---------------- invariants (fp32, per-lane = own sample) ----------------
    const float* fp = Fg + cidx * 9;
    float iv0, iv1, iv2, iv4, iv5;
    {
        float f00=fp[0], f01=fp[1], f02=fp[2];
        float f10=fp[3], f11=fp[4], f12=fp[5];
        float f20=fp[6], f21=fp[7], f22=fp[8];

        float c00 = f00*f00 + f10*f10 + f20*f20;
        float c01 = f00*f01 + f10*f11 + f20*f21;
        float c02 = f00*f02 + f10*f12 + f20*f22;
        float c11 = f01*f01 + f11*f11 + f21*f21;
        float c12 = f01*f02 + f11*f12 + f21*f22;
        float c22 = f02*f02 + f12*f12 + f22*f22;

        float A00 = c11*c22 - c12*c12;
        float A01 = c02*c12 - c01*c22;
        float A02 = c01*c12 - c02*c11;
        float A11 = c00*c22 - c02*c02;
        float A12 = c01*c02 - c00*c12;
        float A22 = c00*c11 - c01*c01;

        iv0 = c00 + c11 + c22;
        iv1 = A00 + A11 + A22;
        iv2 = f00*(f11*f22 - f12*f21) - f01*(f10*f22 - f12*f20) + f02*(f10*f21 - f11*f20);
        iv4 = c00*c00 + c11*c11 + c22*c22;
        iv5 = A00*A00 + A11*A11 + A22*A22;
    }

    // iv packed: elems (I1,I2 | J,-J | I7,I11 | 1,0); k=6 multiplies the b0 column.
    unsigned V01 = cvtpk(iv0, iv1);
    unsigned V23 = cvtpk(iv2, -iv2);
    unsigned V45 = cvtpk(iv4, iv5);
    const unsigned C67 = cvtpk(1.0f, 0.0f);

    float pt_[2];     // per-tile output-dot partial
    float dk[2][4];   // per-tile d accumulator regs 0..3

    #pragma unroll
    for (int t = 0; t < 2; ++t) {
        // B for layer0: tile0 cols = samples of lanes 0..31 (own iv); tile1 cols =
        // samples of lanes 32..63 (partner iv via shfl). Upper-lane slots map to
        // k=8..15 where A is zero, so their contents are don't-care.
        FragU biv;
        if (t == 0) { biv.u[0]=V01;        biv.u[1]=V23;        biv.u[2]=V45;        biv.u[3]=C67; }
        else        { biv.u[0]=pswapu(V01); biv.u[1]=pswapu(V23); biv.u[2]=pswapu(V45); biv.u[3]=C67; }

        f32x16 zz;
        #pragma unroll
        for (int r = 0; r < 16; ++r) zz[r] = 0.f;

        // z0^T = [W0^T|b0] @ [iv;1]
        f32x16 z0 = __builtin_amdgcn_mfma_f32_32x32x16_bf16(w0t.s, biv.s, zz, 0, 0, 0);

        // act0: softplus + sigmoid on C-regs (elementwise, layout-free)
        unsigned hpk[8], s0p[8];
        #pragma unroll
        for (int p = 0; p < 8; ++p) {
            float ha, sa, hb, sb;
            sp_sig(z0[2*p],   ha, sa);
            sp_sig(z0[2*p+1], hb, sb);
            hpk[p] = cvtpk(ha, hb);
            s0p[p] = cvtpk(sa, sb);
        }
        FragU hb0 = bfrag(low, hpk[0], hpk[1], hpk[2], hpk[3]);
        FragU hb1 = bfrag(low, hpk[4], hpk[5], hpk[6], hpk[7]);

        // z1^T = W1^T @ h0^T + b1 (C-init)
        f32x16 z1;
        #pragma unroll
        for (int p = 0; p < 8; ++p) { z1[2*p] = bfl(b1p[p]); z1[2*p+1] = bfh(b1p[p]); }
        z1 = __builtin_amdgcn_mfma_f32_32x32x16_bf16(w1t[0].s, hb0.s, z1, 0, 0, 0);
        z1 = __builtin_amdgcn_mfma_f32_32x32x16_bf16(w1t[1].s, hb1.s, z1, 0, 0, 0);

        // act1 + output partial + g1 = W2 * sig(z1)
        float pt = 0.f;
        unsigned gpk[8];
        #pragma unroll
        for (int p = 0; p < 8; ++p) {
            float h1a, s1a, h1b, s1b;
            sp_sig(z1[2*p],   h1a, s1a);
            sp_sig(z1[2*p+1], h1b, s1b);
            float wa = bfl(w2p[p]), wb = bfh(w2p[p]);
            pt = fmaf(h1a, wa, pt);
            pt = fmaf(h1b, wb, pt);
            gpk[p] = cvtpk(wa * s1a, wb * s1b);
        }
        pt_[t] = pt;
        FragU gb0 = bfrag(low, gpk[0], gpk[1], gpk[2], gpk[3]);
        FragU gb1 = bfrag(low, gpk[4], gpk[5], gpk[6], gpk[7]);

        // gh0^T = W1 @ g1^T
        #pragma unroll
        for (int r = 0; r < 16; ++r) zz[r] = 0.f;
        f32x16 gh = __builtin_amdgcn_mfma_f32_32x32x16_bf16(w1f[0].s, gb0.s, zz, 0, 0, 0);
        gh = __builtin_amdgcn_mfma_f32_32x32x16_bf16(w1f[1].s, gb1.s, gh, 0, 0, 0);

        // g0 = gh0 * s0 (same C-row space as layer0 output)
        unsigned qpk[8];
        #pragma unroll
        for (int p = 0; p < 8; ++p)
            qpk[p] = cvtpk(gh[2*p] * bfl(s0p[p]), gh[2*p+1] * bfh(s0p[p]));
        FragU qb0 = bfrag(low, qpk[0], qpk[1], qpk[2], qpk[3]);
        FragU qb1 = bfrag(low, qpk[4], qpk[5], qpk[6], qpk[7]);

        // d^T = W0 @ g0^T  (only rows 0..5 valid; A zero-padded)
        #pragma unroll
        for (int r = 0; r < 16; ++r) zz[r] = 0.f;
        f32x16 da = __builtin_amdgcn_mfma_f32_32x32x16_bf16(w0b[0].s, qb0.s, zz, 0, 0, 0);
        da = __builtin_amdgcn_mfma_f32_32x32x16_bf16(w0b[1].s, qb1.s, da, 0, 0, 0);
        dk[t][0] = da[0]; dk[t][1] = da[1]; dk[t][2] = da[2]; dk[t][3] = da[3];
    }

    // ---- per-sample scalars from lane-half exchanges (all shfls full-wave) ----
    float po0 = pswapf(pt_[0]);
    float po1 = pswapf(pt_[1]);
    float wvv = (low ? (pt_[0] + po0) : (pt_[1] + po1)) + b2v;

    // C rows: half0 regs0-3 = rows0-3 (d0..d3); half1 regs0,1 = rows4,5 (d4,d5).
    float s10 = pswapf(dk[1][0]), s11 = pswapf(dk[1][1]);
    float s12 = pswapf(dk[1][2]), s13 = pswapf(dk[1][3]);
    float s00 = pswapf(dk[0][0]), s01 = pswapf(dk[0][1]);
    float d0  = low ? dk[0][0] : s10;
    float d1  = low ? dk[0][1] : s11;
    float d2r = low ? dk[0][2] : s12;
    float d3r = low ? dk[0][3] : s13;
    float d4  = low ? s00 : dk[1][0];
    float d5  = low ? s01 : dk[1][1];

    // ---------------- epilogue (fp32): P = F*M + (d2-d3)*cof(F) ----------------
    float f00=fp[0], f01=fp[1], f02=fp[2];
    float f10=fp[3], f11=fp[4], f12=fp[5];
    float f20=fp[6], f21=fp[7], f22=fp[8];

    float c00 = f00*f00 + f10*f10 + f20*f20;
    float c01 = f00*f01 + f10*f11 + f20*f21;
    float c02 = f00*f02 + f10*f12 + f20*f22;
    float c11 = f01*f01 + f11*f11 + f21*f21;
    float c12 = f01*f02 + f11*f12 + f21*f22;
    float c22 = f02*f02 + f12*f12 + f22*f22;

    float A00 = c11*c22 - c12*c12;
    float A01 = c02*c12 - c01*c22;
    float A02 = c01*c12 - c02*c11;
    float A11 = c00*c22 - c02*c02;
    float A12 = c01*c02 - c00*c12;
    float A22 = c00*c11 - c01*c01;

    float cf00 = f11*f22 - f12*f21;
    float cf01 = f12*f20 - f10*f22;
    float cf02 = f10*f21 - f11*f20;
    float cf10 = f02*f21 - f01*f22;
    float cf11 = f00*f22 - f02*f20;
    float cf12 = f01*f20 - f00*f21;
    float cf20 = f01*f12 - f02*f11;
    float cf21 = f02*f10 - f00*f12;
    float cf22 = f00*f11 - f01*f10;
    float J  = f00*cf00 + f01*cf01 + f02*cf02;
    float I1 = c00 + c11 + c22;
    float I11v = A00*A00 + A11*A11 + A22*A22;

    float inv2 = 2.0f * fast_rcp(J * J);

    float T00 = A00*A00*A00 + A11*A01*A01 + A22*A02*A02;
    float T01 = A00*A00*A01 + A11*A01*A11 + A22*A02*A12;
    float T02 = A00*A00*A02 + A11*A01*A12 + A22*A02*A22;
    float T11 = A00*A01*A01 + A11*A11*A11 + A22*A12*A12;
    float T12 = A00*A01*A02 + A11*A11*A12 + A22*A12*A22;
    float T22 = A00*A02*A02 + A11*A12*A12 + A22*A22*A22;

    float G00 = inv2 * (I11v*A00 - T00);
    float G01 = inv2 * (I11v*A01 - T01);
    float G02 = inv2 * (I11v*A02 - T02);
    float G11e= inv2 * (I11v*A11 - T11);
    float G12 = inv2 * (I11v*A12 - T12);
    float G22 = inv2 * (I11v*A22 - T22);

    float aJ  = d2r - d3r;
    float t1  = 2.0f * d0;
    float t2  = 2.0f * d1;
    float t7  = 4.0f * d4;
    float t11 = 2.0f * d5;

    float m00 = t1 + t2*(I1 - c00) + t7*c00 + t11*G00;
    float m01 =      -t2*c01               + t11*G01;
    float m02 =      -t2*c02               + t11*G02;
    float m11 = t1 + t2*(I1 - c11) + t7*c11 + t11*G11e;
    float m12 =      -t2*c12               + t11*G12;
    float m22 = t1 + t2*(I1 - c22) + t7*c22 + t11*G22;

    if (idx < n) {
        float* p = P + idx * 9;
        p[0] = f00*m00 + f01*m01 + f02*m02 + aJ*cf00;
        p[1] = f00*m01 + f01*m11 + f02*m12 + aJ*cf01;
        p[2] = f00*m02 + f01*m12 + f02*m22 + aJ*cf02;
        p[3] = f10*m00 + f11*m01 + f12*m02 + aJ*cf10;
        p[4] = f10*m01 + f11*m11 + f12*m12 + aJ*cf11;
        p[5] = f10*m02 + f11*m12 + f12*m22 + aJ*cf12;
        p[6] = f20*m00 + f21*m01 + f22*m02 + aJ*cf20;
        p[7] = f20*m01 + f21*m11 + f22*m12 + aJ*cf21;
        p[8] = f20*m02 + f21*m12 + f22*m22 + aJ*cf22;
        Wv[idx] = wvv;
    }
}

extern "C" void kernel_launch(void* const* d_in, const int* in_sizes, int n_in,
                              void* d_out, int out_size, void* d_ws, size_t ws_size,
                              hipStream_t stream) {
    const float* F  = (const float*)d_in[0];
    const float* W0 = (const float*)d_in[1];
    const float* b0 = (const float*)d_in[2];
    const float* W1 = (const float*)d_in[3];
    const float* b1 = (const float*)d_in[4];
    const float* W2 = (const float*)d_in[5];
    const float* b2 = (const float*)d_in[6];
    int n = in_sizes[0] / 9;
    float* out = (float*)d_out;
    float* P  = out;                       // [n,3,3] flat
    float* Wv = out + (size_t)n * 9;       // [n,1] flat

    int block = 256;
    int grid = (n + block - 1) / block;
    hipLaunchKernelGGL(energy_kernel, dim3(grid), dim3(block), 0, stream,
                       F, W0, b0, W1, b1, W2, b2, P, Wv, n);
}

// Round 7
// 118.614 us; speedup vs baseline: 38.9675x; 1.1460x over previous
//
#include <hip/hip_runtime.h>
#include <math.h>

typedef __attribute__((ext_vector_type(8)))  short  bf16x8;
typedef __attribute__((ext_vector_type(16))) float  f32x16;

union FragU { unsigned u[4]; bf16x8 s; uint4 q; };

__device__ __forceinline__ float fast_rcp(float x) { return __builtin_amdgcn_rcpf(x); }

// pack two f32 -> two bf16 in one u32 (lo = first elem), RNE
__device__ __forceinline__ unsigned cvtpk(float lo, float hi) {
    unsigned r;
    asm("v_cvt_pk_bf16_f32 %0, %1, %2" : "=v"(r) : "v"(lo), "v"(hi));
    return r;
}
__device__ __forceinline__ unsigned pswapu(unsigned x) { return (unsigned)__shfl_xor((int)x, 32, 64); }
__device__ __forceinline__ float    pswapf(float x)    { return __shfl_xor(x, 32, 64); }
__device__ __forceinline__ float bfl(unsigned p) { return __uint_as_float(p << 16); }
__device__ __forceinline__ float bfh(unsigned p) { return __uint_as_float(p & 0xffff0000u); }

// k-slot permutation: B-slot s = 16f + 8h + 2p + j holds the value that C-reg
// pair (4f+p, elem j) of lane-half h already contains (row of the producing
// MFMA's C layout). Weights contracted over this dim are packed with rho.
__device__ __forceinline__ int rho(int s) {
    int f = s >> 4, h = (s >> 3) & 1, p = (s >> 1) & 3, j = s & 1;
    return 16*f + 4*h + 8*(p >> 1) + 2*(p & 1) + j;
}

// Softplus + sigmoid with HW instructions (v_exp_f32 / v_log_f32 / v_rcp_f32).
__device__ __forceinline__ void sp_sig(float z, float& h, float& s) {
    float az = fabsf(z);
    float e  = __expf(-az);
    float r  = fast_rcp(1.0f + e);
    h = fmaxf(z, 0.0f) + __logf(1.0f + e);
    s = (z >= 0.0f) ? r : (1.0f - r);
}

// ws layout in u32 units:
//  [0..255]     w0t  (4/lane)     [256..767]   w1t (8/lane)
//  [768..1279]  w1f  (8/lane)     [1280..1791] w0b (8/lane)
//  [1792..2303] b1p  (8/lane)     [2304..2815] w2p (8/lane)
//  [2816]       b2 bits
__global__ __launch_bounds__(64) void pack_weights(
    const float* __restrict__ W0, const float* __restrict__ b0,
    const float* __restrict__ W1, const float* __restrict__ b1,
    const float* __restrict__ W2, const float* __restrict__ b2,
    unsigned* __restrict__ ws)
{
    const int lane = threadIdx.x;
    const int col = lane & 31, half = lane >> 5;

    unsigned v[4];
    #pragma unroll
    for (int p = 0; p < 4; ++p) {                    // A = [W0^T | b0 | 0] (K=16, k unpermuted)
        const int k0 = half*8 + 2*p, k1 = k0 + 1;
        float lo = (k0 < 6) ? W0[k0*32 + col] : ((k0 == 6) ? b0[col] : 0.f);
        float hi = (k1 < 6) ? W0[k1*32 + col] : ((k1 == 6) ? b0[col] : 0.f);
        v[p] = cvtpk(lo, hi);
    }
    *(uint4*)(ws + lane*4) = make_uint4(v[0], v[1], v[2], v[3]);

    #pragma unroll
    for (int hf = 0; hf < 2; ++hf) {
        unsigned t[4], fq[4], bq[4];
        #pragma unroll
        for (int p = 0; p < 4; ++p) {
            const int s0 = hf*16 + half*8 + 2*p;
            const int r0 = rho(s0), r1 = r0 + 1;     // rho(s0+1) = rho(s0)+1 (s0 even)
            t[p]  = cvtpk(W1[r0*32 + col], W1[r1*32 + col]);      // A = W1^T, k rho-permuted
            fq[p] = cvtpk(W1[col*32 + r0], W1[col*32 + r1]);      // A = W1,   k rho-permuted
            float lo = (col < 6) ? W0[col*32 + r0] : 0.f;         // A = W0 rows 0..5, k rho-perm
            float hi = (col < 6) ? W0[col*32 + r1] : 0.f;
            bq[p] = cvtpk(lo, hi);
        }
        *(uint4*)(ws + 256  + lane*8 + hf*4) = make_uint4(t[0],  t[1],  t[2],  t[3]);
        *(uint4*)(ws + 768  + lane*8 + hf*4) = make_uint4(fq[0], fq[1], fq[2], fq[3]);
        *(uint4*)(ws + 1280 + lane*8 + hf*4) = make_uint4(bq[0], bq[1], bq[2], bq[3]);
    }

    unsigned bp[8], wp[8];
    #pragma unroll
    for (int p = 0; p < 8; ++p) {                    // C-layout register pairs
        const int r0 = 2*p, r1 = r0 + 1;
        const int R0 = (r0 & 3) + 8*(r0 >> 2) + 4*half;
        const int R1 = (r1 & 3) + 8*(r1 >> 2) + 4*half;
        bp[p] = cvtpk(b1[R0], b1[R1]);
        wp[p] = cvtpk(W2[R0], W2[R1]);
    }
    *(uint4*)(ws + 1792 + lane*8)     = make_uint4(bp[0], bp[1], bp[2], bp[3]);
    *(uint4*)(ws + 1792 + lane*8 + 4) = make_uint4(bp[4], bp[5], bp[6], bp[7]);
    *(uint4*)(ws + 2304 + lane*8)     = make_uint4(wp[0], wp[1], wp[2], wp[3]);
    *(uint4*)(ws + 2304 + lane*8 + 4) = make_uint4(wp[4], wp[5], wp[6], wp[7]);
    if (lane == 0) ws[2816] = __float_as_uint(b2[0]);
}

__global__ __launch_bounds__(256) void energy_kernel(
    const float* __restrict__ Fg,
    const unsigned* __restrict__ ws,
    float* __restrict__ P, float* __restrict__ Wv, int n)
{
    const int  tid  = threadIdx.x;
    const int  lane = tid & 63;
    const int  wid  = tid >> 6;
    const bool low  = (lane >> 5) == 0;
    const long idx  = ((long)blockIdx.x * 4 + wid) * 64 + lane;
    const long cidx = (idx < n) ? idx : 0;

    // ---------------- packed weight fragments: coalesced reloads ----------------
    FragU w0t, w1t[2], w1f[2], w0b[2];
    w0t.q    = *(const uint4*)(ws + lane*4);
    w1t[0].q = *(const uint4*)(ws + 256  + lane*8);
    w1t[1].q = *(const uint4*)(ws + 256  + lane*8 + 4);
    w1f[0].q = *(const uint4*)(ws + 768  + lane*8);
    w1f[1].q = *(const uint4*)(ws + 768  + lane*8 + 4);
    w0b[0].q = *(const uint4*)(ws + 1280 + lane*8);
    w0b[1].q = *(const uint4*)(ws + 1280 + lane*8 + 4);
    uint4 b1q0 = *(const uint4*)(ws + 1792 + lane*8);
    uint4 b1q1 = *(const uint4*)(ws + 1792 + lane*8 + 4);
    uint4 w2q0 = *(const uint4*)(ws + 2304 + lane*8);
    uint4 w2q1 = *(const uint4*)(ws + 2304 + lane*8 + 4);
    unsigned b1p[8] = {b1q0.x, b1q0.y, b1q0.z, b1q0.w, b1q1.x, b1q1.y, b1q1.z, b1q1.w};
    unsigned w2p[8] = {w2q0.x, w2q0.y, w2q0.z, w2q0.w, w2q1.x, w2q1.y, w2q1.z, w2q1.w};
    const float b2v = __uint_as_float(ws[2816]);

    // ---------------- invariants (fp32, per-lane = own sample) ----------------
    const float* fp = Fg + cidx * 9;
    float iv0, iv1, iv2, iv4, iv5;
    {
        float f00=fp[0], f01=fp[1], f02=fp[2];
        float f10=fp[3], f11=fp[4], f12=fp[5];
        float f20=fp[6], f21=fp[7], f22=fp[8];

        float c00 = f00*f00 + f10*f10 + f20*f20;
        float c01 = f00*f01 + f10*f11 + f20*f21;
        float c02 = f00*f02 + f10*f12 + f20*f22;
        float c11 = f01*f01 + f11*f11 + f21*f21;
        float c12 = f01*f02 + f11*f12 + f21*f22;
        float c22 = f02*f02 + f12*f12 + f22*f22;

        float A00 = c11*c22 - c12*c12;
        float A01 = c02*c12 - c01*c22;
        float A02 = c01*c12 - c02*c11;
        float A11 = c00*c22 - c02*c02;
        float A12 = c01*c02 - c00*c12;
        float A22 = c00*c11 - c01*c01;

        iv0 = c00 + c11 + c22;
        iv1 = A00 + A11 + A22;
        iv2 = f00*(f11*f22 - f12*f21) - f01*(f10*f22 - f12*f20) + f02*(f10*f21 - f11*f20);
        iv4 = c00*c00 + c11*c11 + c22*c22;
        iv5 = A00*A00 + A11*A11 + A22*A22;
    }

    // iv packed: (I1,I2 | J,-J | I7,I11 | 1,0); k=6 multiplies the b0 column.
    unsigned V01 = cvtpk(iv0, iv1);
    unsigned V23 = cvtpk(iv2, -iv2);
    unsigned V45 = cvtpk(iv4, iv5);
    const unsigned C67 = cvtpk(1.0f, 0.0f);
    // tile-1 B: lower lanes need partner's invariants; upper slots hit zero A cols.
    unsigned S01 = pswapu(V01);
    unsigned S23 = pswapu(V23);
    unsigned S45 = pswapu(V45);

    f32x16 zero16;
    #pragma unroll
    for (int r = 0; r < 16; ++r) zero16[r] = 0.f;

    float pt_[2];     // per-tile output-dot partial
    float dk[2][4];   // per-tile d accumulator regs 0..3

    #pragma unroll
    for (int t = 0; t < 2; ++t) {
        FragU biv;
        if (t == 0) { biv.u[0]=V01; biv.u[1]=V23; biv.u[2]=V45; biv.u[3]=C67; }
        else        { biv.u[0]=S01; biv.u[1]=S23; biv.u[2]=S45; biv.u[3]=C67; }

        // z0^T = [W0^T|b0] @ [iv;1]
        f32x16 z0 = __builtin_amdgcn_mfma_f32_32x32x16_bf16(w0t.s, biv.s, zero16, 0, 0, 0);

        // act0; B-fragments are pure register renames (rho-packed consumers)
        FragU hbf[2]; unsigned s0p[8];
        #pragma unroll
        for (int p = 0; p < 8; ++p) {
            float ha, sa, hb, sb;
            sp_sig(z0[2*p],   ha, sa);
            sp_sig(z0[2*p+1], hb, sb);
            hbf[p >> 2].u[p & 3] = cvtpk(ha, hb);
            s0p[p] = cvtpk(sa, sb);
        }

        // z1^T = W1^T(rho) @ h0^T + b1 (C-init)
        f32x16 z1;
        #pragma unroll
        for (int p = 0; p < 8; ++p) { z1[2*p] = bfl(b1p[p]); z1[2*p+1] = bfh(b1p[p]); }
        z1 = __builtin_amdgcn_mfma_f32_32x32x16_bf16(w1t[0].s, hbf[0].s, z1, 0, 0, 0);
        z1 = __builtin_amdgcn_mfma_f32_32x32x16_bf16(w1t[1].s, hbf[1].s, z1, 0, 0, 0);

        // act1 + output partial + g1 = W2 * sig(z1)
        float pt = 0.f;
        FragU gbf[2];
        #pragma unroll
        for (int p = 0; p < 8; ++p) {
            float h1a, s1a, h1b, s1b;
            sp_sig(z1[2*p],   h1a, s1a);
            sp_sig(z1[2*p+1], h1b, s1b);
            float wa = bfl(w2p[p]), wb = bfh(w2p[p]);
            pt = fmaf(h1a, wa, pt);
            pt = fmaf(h1b, wb, pt);
            gbf[p >> 2].u[p & 3] = cvtpk(wa * s1a, wb * s1b);
        }
        pt_[t] = pt;

        // gh0^T = W1(rho) @ g1^T
        f32x16 gh = __builtin_amdgcn_mfma_f32_32x32x16_bf16(w1f[0].s, gbf[0].s, zero16, 0, 0, 0);
        gh = __builtin_amdgcn_mfma_f32_32x32x16_bf16(w1f[1].s, gbf[1].s, gh, 0, 0, 0);

        // g0 = gh0 * s0 (same C space as layer-0 output)
        FragU qbf[2];
        #pragma unroll
        for (int p = 0; p < 8; ++p)
            qbf[p >> 2].u[p & 3] = cvtpk(gh[2*p] * bfl(s0p[p]), gh[2*p+1] * bfh(s0p[p]));

        // d^T = W0(rho) @ g0^T  (rows 0..5 valid)
        f32x16 da = __builtin_amdgcn_mfma_f32_32x32x16_bf16(w0b[0].s, qbf[0].s, zero16, 0, 0, 0);
        da = __builtin_amdgcn_mfma_f32_32x32x16_bf16(w0b[1].s, qbf[1].s, da, 0, 0, 0);
        dk[t][0] = da[0]; dk[t][1] = da[1]; dk[t][2] = da[2]; dk[t][3] = da[3];
    }

    // ---- per-sample scalars from lane-half exchanges (round-5 proven) ----
    float po0 = pswapf(pt_[0]);
    float po1 = pswapf(pt_[1]);
    float wvv = (low ? (pt_[0] + po0) : (pt_[1] + po1)) + b2v;

    // C rows: half0 regs0-3 = rows0-3 (d0..d3); half1 regs0,1 = rows4,5 (d4,d5).
    float s10 = pswapf(dk[1][0]), s11 = pswapf(dk[1][1]);
    float s12 = pswapf(dk[1][2]), s13 = pswapf(dk[1][3]);
    float s00 = pswapf(dk[0][0]), s01 = pswapf(dk[0][1]);
    float d0  = low ? dk[0][0] : s10;
    float d1  = low ? dk[0][1] : s11;
    float d2r = low ? dk[0][2] : s12;
    float d3r = low ? dk[0][3] : s13;
    float d4  = low ? s00 : dk[1][0];
    float d5  = low ? s01 : dk[1][1];

    // ---------------- epilogue (fp32): P = F*M + (d2-d3)*cof(F) ----------------
    float f00=fp[0], f01=fp[1], f02=fp[2];
    float f10=fp[3], f11=fp[4], f12=fp[5];
    float f20=fp[6], f21=fp[7], f22=fp[8];

    float c00 = f00*f00 + f10*f10 + f20*f20;
    float c01 = f00*f01 + f10*f11 + f20*f21;
    float c02 = f00*f02 + f10*f12 + f20*f22;
    float c11 = f01*f01 + f11*f11 + f21*f21;
    float c12 = f01*f02 + f11*f12 + f21*f22;
    float c22 = f02*f02 + f12*f12 + f22*f22;

    float A00 = c11*c22 - c12*c12;
    float A01 = c02*c12 - c01*c22;
    float A02 = c01*c12 - c02*c11;
    float A11 = c00*c22 - c02*c02;
    float A12 = c01*c02 - c00*c12;
    float A22 = c00*c11 - c01*c01;

    float cf00 = f11*f22 - f12*f21;
    float cf01 = f12*f20 - f10*f22;
    float cf02 = f10*f21 - f11*f20;
    float cf10 = f02*f21 - f01*f22;
    float cf11 = f00*f22 - f02*f20;
    float cf12 = f01*f20 - f00*f21;
    float cf20 = f01*f12 - f02*f11;
    float cf21 = f02*f10 - f00*f12;
    float cf22 = f00*f11 - f01*f10;
    float J  = f00*cf00 + f01*cf01 + f02*cf02;
    float I1 = c00 + c11 + c22;
    float I11v = A00*A00 + A11*A11 + A22*A22;

    float inv2 = 2.0f * fast_rcp(J * J);

    float T00 = A00*A00*A00 + A11*A01*A01 + A22*A02*A02;
    float T01 = A00*A00*A01 + A11*A01*A11 + A22*A02*A12;
    float T02 = A00*A00*A02 + A11*A01*A12 + A22*A02*A22;
    float T11 = A00*A01*A01 + A11*A11*A11 + A22*A12*A12;
    float T12 = A00*A01*A02 + A11*A11*A12 + A22*A12*A22;
    float T22 = A00*A02*A02 + A11*A12*A12 + A22*A22*A22;

    float G00 = inv2 * (I11v*A00 - T00);
    float G01 = inv2 * (I11v*A01 - T01);
    float G02 = inv2 * (I11v*A02 - T02);
    float G11e= inv2 * (I11v*A11 - T11);
    float G12 = inv2 * (I11v*A12 - T12);
    float G22 = inv2 * (I11v*A22 - T22);

    float aJ  = d2r - d3r;
    float t1  = 2.0f * d0;
    float t2  = 2.0f * d1;
    float t7  = 4.0f * d4;
    float t11 = 2.0f * d5;

    float m00 = t1 + t2*(I1 - c00) + t7*c00 + t11*G00;
    float m01 =      -t2*c01               + t11*G01;
    float m02 =      -t2*c02               + t11*G02;
    float m11 = t1 + t2*(I1 - c11) + t7*c11 + t11*G11e;
    float m12 =      -t2*c12               + t11*G12;
    float m22 = t1 + t2*(I1 - c22) + t7*c22 + t11*G22;

    if (idx < n) {
        float* p = P + idx * 9;
        p[0] = f00*m00 + f01*m01 + f02*m02 + aJ*cf00;
        p[1] = f00*m01 + f01*m11 + f02*m12 + aJ*cf01;
        p[2] = f00*m02 + f01*m12 + f02*m22 + aJ*cf02;
        p[3] = f10*m00 + f11*m01 + f12*m02 + aJ*cf10;
        p[4] = f10*m01 + f11*m11 + f12*m12 + aJ*cf11;
        p[5] = f10*m02 + f11*m12 + f12*m22 + aJ*cf12;
        p[6] = f20*m00 + f21*m01 + f22*m02 + aJ*cf20;
        p[7] = f20*m01 + f21*m11 + f22*m12 + aJ*cf21;
        p[8] = f20*m02 + f21*m12 + f22*m22 + aJ*cf22;
        Wv[idx] = wvv;
    }
}

extern "C" void kernel_launch(void* const* d_in, const int* in_sizes, int n_in,
                              void* d_out, int out_size, void* d_ws, size_t ws_size,
                              hipStream_t stream) {
    const float* F  = (const float*)d_in[0];
    const float* W0 = (const float*)d_in[1];
    const float* b0 = (const float*)d_in[2];
    const float* W1 = (const float*)d_in[3];
    const float* b1 = (const float*)d_in[4];
    const float* W2 = (const float*)d_in[5];
    const float* b2 = (const float*)d_in[6];
    int n = in_sizes[0] / 9;
    float* out = (float*)d_out;
    float* P  = out;                       // [n,3,3] flat
    float* Wv = out + (size_t)n * 9;       // [n,1] flat
    unsigned* ws = (unsigned*)d_ws;

    hipLaunchKernelGGL(pack_weights, dim3(1), dim3(64), 0, stream,
                       W0, b0, W1, b1, W2, b2, ws);

    int block = 256;
    int grid = (n + block - 1) / block;
    hipLaunchKernelGGL(energy_kernel, dim3(grid), dim3(block), 0, stream,
                       F, ws, P, Wv, n);
}